// Round 7
// baseline (335.781 us; speedup 1.0000x reference)
//
#include <hip/hip_runtime.h>
#include <math.h>

#define Bc 64
#define Nc 4
#define Ac 1024
#define Oc 128
#define Dc 256
#define Qc 256
#define Hc 128
#define BN (Bc*Nc)

using f4     = __attribute__((ext_vector_type(4))) float;
using f32x4  = __attribute__((ext_vector_type(4))) float;
using short8 = __attribute__((ext_vector_type(8))) short;
using us4    = __attribute__((ext_vector_type(4))) unsigned short;

__device__ inline float decode_t(const void* p) {
    int i = *(const int*)p;
    if (i >= 1 && i <= 1000000) return (float)i;
    return __int_as_float(i);
}

// round-to-nearest-even fp32 -> bf16
__device__ inline unsigned short bf16_rne(float x) {
    unsigned u = __builtin_bit_cast(unsigned, x);
    u += 0x7FFFu + ((u >> 16) & 1u);
    return (unsigned short)(u >> 16);
}

// split fp32 -> truncated bf16 hi + bf16(residual) lo.  x ~= hi + lo
__device__ inline void split_bf16(float x, unsigned short& hi, unsigned short& lo) {
    unsigned u = __builtin_bit_cast(unsigned, x);
    hi = (unsigned short)(u >> 16);
    float hif = __builtin_bit_cast(float, u & 0xFFFF0000u);
    float lof = x - hif;
    lo = (unsigned short)(__builtin_bit_cast(unsigned, lof) >> 16);
}

// VALU-only lane reduce within 16-lane rows via DPP row_ror (no LDS pipe).
template<int CTRL>
__device__ inline float dpp_ror_add(float x) {
    int yi = __builtin_amdgcn_update_dpp(0, __builtin_bit_cast(int, x),
                                         CTRL, 0xf, 0xf, true);
    return x + __builtin_bit_cast(float, yi);
}
__device__ inline float row16_sum(float v) {
    v = dpp_ror_add<0x128>(v);   // row_ror:8
    v = dpp_ror_add<0x124>(v);   // row_ror:4
    v = dpp_ror_add<0x122>(v);   // row_ror:2
    v = dpp_ror_add<0x121>(v);   // row_ror:1
    return v;
}

__device__ inline short8 pack_hi(const f4& a, const f4& b,
                                 short8& lo_out) {
    short8 hi;
    unsigned short h16, l16;
    #pragma unroll
    for (int j = 0; j < 4; j++) {
        split_bf16(a[j], h16, l16); hi[j] = (short)h16; lo_out[j] = (short)l16;
    }
    #pragma unroll
    for (int j = 0; j < 4; j++) {
        split_bf16(b[j], h16, l16); hi[4+j] = (short)h16; lo_out[4+j] = (short)l16;
    }
    return hi;
}

// ---------------------------------------------------------------------------
// prep_fused: ONE prep launch.
//   blocks 0..511  : Mt[b][h][o] = sum_d W1[d][h]*obj[b][o][d] via MFMA.
//                    A (W1T) and B (obj) fragments built by DIRECT fp32 loads
//                    + in-register hi/lo split — no prep_split, no staging
//                    workspace, no LDS.
//   blocks 512..767: qb[bn,h] = q[bn,:] @ W1q + b1[h].
// ---------------------------------------------------------------------------
__global__ __launch_bounds__(256, 2) void prep_fused_kernel(
    const float* __restrict__ obj, const float* __restrict__ W1,
    const float* __restrict__ q,   const float* __restrict__ b1,
    unsigned short* __restrict__ Mt_hi, unsigned short* __restrict__ Mt_lo,
    float* __restrict__ qb)
{
    __shared__ float qs[256];
    __shared__ float red[2][128];

    const int bid = blockIdx.x;
    const int t   = threadIdx.x;

    if (bid < 512) {
        // ---- M2 branch: 64h x 32o tile ----
        const int b    = bid >> 3;
        const int rr   = bid & 7;
        const int h0   = (rr & 1) * 64;
        const int o0   = (rr >> 1) * 32;
        const int wave = t >> 6, lane = t & 63;
        const int l15  = lane & 15, quad = lane >> 4;
        const int hh   = h0 + wave * 16 + l15;    // this lane's A row (h)

        // A fragments: W1[d][hh], d = ks*32 + quad*8 + j ; split in regs.
        // Per load instr the wave touches 4 d-rows x 16 consecutive h = 4 lines.
        short8 Ah[8], Al[8];
        #pragma unroll
        for (int ks = 0; ks < 8; ks++) {
            const int ko = ks * 32 + quad * 8;
            #pragma unroll
            for (int j = 0; j < 8; j++) {
                unsigned short h16, l16;
                split_bf16(W1[(size_t)(ko + j) * Hc + hh], h16, l16);
                Ah[ks][j] = (short)h16; Al[ks][j] = (short)l16;
            }
        }

        const float* ob0 = obj + ((size_t)b * Oc + o0 + l15) * Dc;
        const float* ob1 = obj + ((size_t)b * Oc + o0 + 16 + l15) * Dc;

        f32x4 acc0 = (f32x4)(0.f), acc1 = (f32x4)(0.f);
        #pragma unroll
        for (int ks = 0; ks < 8; ks++) {
            const int ko = ks * 32 + quad * 8;
            short8 B0l, B1l;
            short8 B0h = pack_hi(*(const f4*)(ob0 + ko), *(const f4*)(ob0 + ko + 4), B0l);
            short8 B1h = pack_hi(*(const f4*)(ob1 + ko), *(const f4*)(ob1 + ko + 4), B1l);
            acc0 = __builtin_amdgcn_mfma_f32_16x16x32_bf16(Al[ks], B0l, acc0, 0, 0, 0);
            acc0 = __builtin_amdgcn_mfma_f32_16x16x32_bf16(Al[ks], B0h, acc0, 0, 0, 0);
            acc0 = __builtin_amdgcn_mfma_f32_16x16x32_bf16(Ah[ks], B0l, acc0, 0, 0, 0);
            acc0 = __builtin_amdgcn_mfma_f32_16x16x32_bf16(Ah[ks], B0h, acc0, 0, 0, 0);
            acc1 = __builtin_amdgcn_mfma_f32_16x16x32_bf16(Al[ks], B1l, acc1, 0, 0, 0);
            acc1 = __builtin_amdgcn_mfma_f32_16x16x32_bf16(Al[ks], B1h, acc1, 0, 0, 0);
            acc1 = __builtin_amdgcn_mfma_f32_16x16x32_bf16(Ah[ks], B1l, acc1, 0, 0, 0);
            acc1 = __builtin_amdgcn_mfma_f32_16x16x32_bf16(Ah[ks], B1h, acc1, 0, 0, 0);
        }

        // C/D layout: col = l15 (o), row = quad*4 + r (h)
        #pragma unroll
        for (int r = 0; r < 4; r++) {
            int hrow = h0 + wave * 16 + quad * 4 + r;
            size_t base = ((size_t)b * Hc + hrow) * Oc + o0 + l15;
            unsigned short hh16, ll16;
            split_bf16(acc0[r], hh16, ll16);
            Mt_hi[base] = hh16; Mt_lo[base] = ll16;
            split_bf16(acc1[r], hh16, ll16);
            Mt_hi[base + 16] = hh16; Mt_lo[base + 16] = ll16;
        }
    } else {
        // ---- qb branch ----
        const int bn = bid - 512;
        qs[t] = q[bn * Qc + t];
        __syncthreads();

        const int h = t & 127, kq = t >> 7;   // kq = 0..1, 128 d each
        float acc = 0.f;
        const float* w = W1 + (size_t)(Dc + kq * 128) * Hc + h;
        #pragma unroll 8
        for (int d = 0; d < 128; ++d)
            acc += qs[kq * 128 + d] * w[(size_t)d * Hc];
        red[kq][h] = acc;
        __syncthreads();

        if (t < 128)
            qb[bn * Hc + t] = b1[t] + red[0][t] + red[1][t];
    }
}

// ---------------------------------------------------------------------------
// main_half: grid (512) = 2 blocks per bn, 512 thr, 2 blocks/CU.
// R7: finalize fused in via fence + atomicExch race-winner — the second
// half-block to finish combines both halves and writes out[bn].
// Works for ANY initial flag value (poisoned ws): a block finalizes iff
// the exchanged-out value equals the OTHER half's magic; stale flags from
// a previous (deterministic, identical) iteration at worst make both
// blocks write identical outputs. z_part padded to 128B/blk so halves
// never share a cache line.
// ---------------------------------------------------------------------------
#define MAGIC 0x3A9F17C0u

__global__ __launch_bounds__(512, 4) void main_half_kernel(
    const float* __restrict__ att1, const int* __restrict__ tags,
    const unsigned short* __restrict__ Mt_hi, const unsigned short* __restrict__ Mt_lo,
    const float* __restrict__ qb, const float* __restrict__ W2,
    const float* __restrict__ b2, const void* __restrict__ tptr,
    float* __restrict__ out_part, float* __restrict__ z_part,
    unsigned* __restrict__ flags, float* __restrict__ out)
{
    __shared__ unsigned short A_s[64][136];   // bf16 tile for MFMA, 17.4 KB
    __shared__ float part2[64][9];            // logit partials, +1 pad
    __shared__ float part3[16][132];          // end-of-kernel o-reduce, 8.4 KB
    __shared__ float e_s[64];
    __shared__ float qb_s[128], w2_s[128];
    __shared__ int win_s;

    const int t    = threadIdx.x;
    const int lane = t & 63;
    const int wave = t >> 6;          // 0..7
    const int l15  = lane & 15;
    const int quad = lane >> 4;
    const int blk  = blockIdx.x;      // 0..511
    const int bn   = blk >> 1;
    const int half = blk & 1;
    const int b    = bn >> 2;
    const int hw   = wave * 16;       // h-group base
    const int g3   = t >> 5;          // owned row group 0..15
    const int o4   = (t & 31) * 4;    // owned o base (4 consecutive o)

    const float* att_half = att1 + ((size_t)bn * Ac + half * 512) * Oc;

    // ---- prologue: tile-0 staging loads (HBM) ----
    f4 sv[4];
    #pragma unroll
    for (int s = 0; s < 4; s++) {
        int idx = t + 512 * s;
        sv[s] = *(const f4*)(att_half + (size_t)idx * 4);
    }

    // ---- B fragments (hi/lo), once per block ----
    const size_t brow = ((size_t)b * Hc + hw + l15) * Oc;
    short8 Bh[4], Bl[4];
    #pragma unroll
    for (int ks = 0; ks < 4; ks++) {
        const int ko = ks * 32 + quad * 8;
        Bh[ks] = *(const short8*)(Mt_hi + brow + ko);
        Bl[ks] = *(const short8*)(Mt_lo + brow + ko);
    }

    if (t < 128) { qb_s[t] = qb[bn * Hc + t]; w2_s[t] = W2[t]; }
    int tg_cur = (t < 64) ? tags[(size_t)bn * Ac + half * 512 + t] : 0;
    const float b2v  = b2[0];
    const float tval = decode_t(tptr);

    float z_reg = 0.f;
    f4 out4 = {0.f, 0.f, 0.f, 0.f};   // this thread's out[o4..o4+3] partial

    for (int tile = 0; tile < 8; ++tile) {
        // ---- stage bf16 into LDS (sv stays live for phase 3) ----
        #pragma unroll
        for (int s = 0; s < 4; s++) {
            int idx = t + 512 * s;
            int r = idx >> 5, c4 = idx & 31;
            us4 h4;
            #pragma unroll
            for (int j = 0; j < 4; j++) h4[j] = bf16_rne(sv[s][j]);
            *(us4*)&A_s[r][c4 * 4] = h4;
        }
        __syncthreads();

        // ---- prefetch next tile into nv (in flight through this tile) ----
        f4 nv[4];
        int tg_next = 0;
        if (tile < 7) {
            const float* np = att_half + (size_t)(tile + 1) * 64 * Oc;
            #pragma unroll
            for (int s = 0; s < 4; s++) {
                int idx = t + 512 * s;
                nv[s] = *(const f4*)(np + (size_t)idx * 4);
            }
            if (t < 64) tg_next = tags[(size_t)bn * Ac + half * 512 + (tile + 1) * 64 + t];
        }

        // ---- MFMA: A_rne * (Bhi + Blo) ----
        f32x4 acc[4];
        #pragma unroll
        for (int i = 0; i < 4; i++) acc[i] = (f32x4)(0.f);
        #pragma unroll
        for (int ks = 0; ks < 4; ks++) {
            const int ko = ks * 32 + quad * 8;
            #pragma unroll
            for (int i = 0; i < 4; i++) {
                short8 ah = *(const short8*)&A_s[i * 16 + l15][ko];
                acc[i] = __builtin_amdgcn_mfma_f32_16x16x32_bf16(ah, Bh[ks], acc[i], 0, 0, 0);
                acc[i] = __builtin_amdgcn_mfma_f32_16x16x32_bf16(ah, Bl[ks], acc[i], 0, 0, 0);
            }
        }

        // ---- epilogue: +qb, relu, *W2; DPP row-reduce over the 16 h lanes ----
        // C/D layout: col(h) = l15, row(a) = i*16 + quad*4 + r
        {
            const float qbv = qb_s[hw + l15], w2v = w2_s[hw + l15];
            #pragma unroll
            for (int i = 0; i < 4; i++)
                #pragma unroll
                for (int r = 0; r < 4; r++) {
                    float v = acc[i][r] + qbv;
                    v = v > 0.f ? v : 0.f;
                    float s = row16_sum(v * w2v);   // VALU DPP, no LDS
                    if (l15 == 0)
                        part2[i * 16 + quad * 4 + r][wave] = s;
                }
        }
        __syncthreads();

        // ---- masked exp; accumulate Z in registers (wave 0 only) ----
        if (t < 64) {
            float sum = b2v;
            #pragma unroll
            for (int x = 0; x < 8; x++) sum += part2[t][x];
            float logit = sum / tval;
            float e = (tg_cur > 0) ? __expf(logit) : 0.f;
            e_s[t] = e;
            z_reg += e;
        }
        __syncthreads();

        // ---- phase 3: out4 += e[row]*sv — registers, zero tile LDS ----
        #pragma unroll
        for (int s = 0; s < 4; s++) {
            const float ev = e_s[g3 + 16 * s];
            out4[0] += ev * sv[s][0];
            out4[1] += ev * sv[s][1];
            out4[2] += ev * sv[s][2];
            out4[3] += ev * sv[s][3];
        }

        // ---- rotate prefetched tile in ----
        #pragma unroll
        for (int s = 0; s < 4; s++) sv[s] = nv[s];
        tg_cur = tg_next;
    }

    // ---- write this half's partials ----
    __syncthreads();
    *(f4*)&part3[g3][o4] = out4;
    __syncthreads();
    if (t < 128) {
        float s = 0.f;
        #pragma unroll
        for (int g = 0; g < 16; g++) s += part3[g][t];
        out_part[(size_t)blk * 128 + t] = s;
    }
    if (t < 64) {   // all z_reg live in wave 0
        float z = z_reg;
        #pragma unroll
        for (int off = 32; off > 0; off >>= 1) z += __shfl_down(z, off);
        if (t == 0) z_part[(size_t)blk * 32] = z;   // 128B stride: no line sharing
    }

    // ---- fused finalize: second half-block to arrive combines ----
    __threadfence();
    __syncthreads();
    if (t == 0) {
        unsigned old = atomicExch(&flags[bn], MAGIC | (unsigned)half);
        win_s = (old == (MAGIC | (unsigned)(half ^ 1)));
    }
    __syncthreads();
    if (win_s && t < 128) {
        float Z = z_part[(size_t)(bn * 2) * 32] + z_part[(size_t)(bn * 2 + 1) * 32];
        float v = out_part[(size_t)(bn * 2) * 128 + t]
                + out_part[(size_t)(bn * 2 + 1) * 128 + t];
        out[(size_t)bn * Oc + t] = v / Z;
    }
}

extern "C" void kernel_launch(void* const* d_in, const int* in_sizes, int n_in,
                              void* d_out, int out_size, void* d_ws, size_t ws_size,
                              hipStream_t stream)
{
    (void)in_sizes; (void)n_in; (void)out_size; (void)ws_size;

    const float* q    = (const float*)d_in[0];
    const float* att1 = (const float*)d_in[1];
    const float* obj  = (const float*)d_in[2];
    const int*   tags = (const int*)d_in[3];
    const float* W1   = (const float*)d_in[4];
    const float* b1   = (const float*)d_in[5];
    const float* W2   = (const float*)d_in[6];
    const float* b2   = (const float*)d_in[7];
    const void*  tptr = (const void*)d_in[8];
    float* out = (float*)d_out;

    char* wsb = (char*)d_ws;
    unsigned short* Mt_hi = (unsigned short*)wsb;                          // 2 MB
    unsigned short* Mt_lo = (unsigned short*)(wsb + (size_t)2*1024*1024);  // 2 MB
    float* qbuf     = (float*)   (wsb + (size_t)4*1024*1024);  // 128 KB
    float* out_part = (float*)   (wsb + (size_t)5*1024*1024);  // 256 KB
    float* z_part   = (float*)   (wsb + (size_t)6*1024*1024);  // 64 KB (stride 32)
    unsigned* flags = (unsigned*)(wsb + (size_t)7*1024*1024);  // 1 KB

    prep_fused_kernel<<<dim3(512 + BN), 256, 0, stream>>>(obj, W1, q, b1,
                                                          Mt_hi, Mt_lo, qbuf);
    main_half_kernel<<<dim3(2 * BN), 512, 0, stream>>>(att1, tags, Mt_hi, Mt_lo,
                                                       qbuf, W2, b2, tptr,
                                                       out_part, z_part, flags, out);
}

// Round 8
// 240.628 us; speedup vs baseline: 1.3954x; 1.3954x over previous
//
#include <hip/hip_runtime.h>
#include <math.h>

#define Bc 64
#define Nc 4
#define Ac 1024
#define Oc 128
#define Dc 256
#define Qc 256
#define Hc 128
#define BN (Bc*Nc)

using f4     = __attribute__((ext_vector_type(4))) float;
using f32x4  = __attribute__((ext_vector_type(4))) float;
using short8 = __attribute__((ext_vector_type(8))) short;
using us4    = __attribute__((ext_vector_type(4))) unsigned short;

__device__ inline float decode_t(const void* p) {
    int i = *(const int*)p;
    if (i >= 1 && i <= 1000000) return (float)i;
    return __int_as_float(i);
}

// round-to-nearest-even fp32 -> bf16
__device__ inline unsigned short bf16_rne(float x) {
    unsigned u = __builtin_bit_cast(unsigned, x);
    u += 0x7FFFu + ((u >> 16) & 1u);
    return (unsigned short)(u >> 16);
}

// split fp32 -> truncated bf16 hi + bf16(residual) lo.  x ~= hi + lo
__device__ inline void split_bf16(float x, unsigned short& hi, unsigned short& lo) {
    unsigned u = __builtin_bit_cast(unsigned, x);
    hi = (unsigned short)(u >> 16);
    float hif = __builtin_bit_cast(float, u & 0xFFFF0000u);
    float lof = x - hif;
    lo = (unsigned short)(__builtin_bit_cast(unsigned, lof) >> 16);
}

// VALU-only lane reduce within 16-lane rows via DPP row_ror (no LDS pipe).
template<int CTRL>
__device__ inline float dpp_ror_add(float x) {
    int yi = __builtin_amdgcn_update_dpp(0, __builtin_bit_cast(int, x),
                                         CTRL, 0xf, 0xf, true);
    return x + __builtin_bit_cast(float, yi);
}
__device__ inline float row16_sum(float v) {
    v = dpp_ror_add<0x128>(v);   // row_ror:8
    v = dpp_ror_add<0x124>(v);   // row_ror:4
    v = dpp_ror_add<0x122>(v);   // row_ror:2
    v = dpp_ror_add<0x121>(v);   // row_ror:1
    return v;
}

// ---------------------------------------------------------------------------
// prep_combined: ONE launch.
//   blocks 0..1023   : split obj fp32 -> bf16 hi/lo (8 elems/thread)
//   blocks 1024..1031: transpose+split W1[0:256][:] -> W1T hi/lo [128][256]
//   blocks 1032..1287: qb[bn,h] = q[bn,:] @ W1q + b1[h]   (256-thr variant)
// ---------------------------------------------------------------------------
__global__ __launch_bounds__(256) void prep_combined_kernel(
    const float* __restrict__ obj, const float* __restrict__ W1,
    const float* __restrict__ q,   const float* __restrict__ b1,
    unsigned short* __restrict__ obj_hi, unsigned short* __restrict__ obj_lo,
    unsigned short* __restrict__ W1T_hi, unsigned short* __restrict__ W1T_lo,
    float* __restrict__ qb)
{
    __shared__ float Ts[64][65];
    __shared__ float qs[256];
    __shared__ float red[2][128];
    const int t = threadIdx.x;
    const int bid = blockIdx.x;

    if (bid < 1024) {
        size_t i0 = ((size_t)bid * 256 + t) * 8;
        f4 v0 = *(const f4*)(obj + i0);
        f4 v1 = *(const f4*)(obj + i0 + 4);
        short8 hi, lo;
        unsigned short h16, l16;
        #pragma unroll
        for (int j = 0; j < 4; j++) {
            split_bf16(v0[j], h16, l16); hi[j] = (short)h16; lo[j] = (short)l16;
        }
        #pragma unroll
        for (int j = 0; j < 4; j++) {
            split_bf16(v1[j], h16, l16); hi[4 + j] = (short)h16; lo[4 + j] = (short)l16;
        }
        *(short8*)(obj_hi + i0) = hi;
        *(short8*)(obj_lo + i0) = lo;
    } else if (bid < 1032) {
        const int wb = bid - 1024;            // 0..7
        const int d0 = (wb & 3) * 64, h0 = (wb >> 2) * 64;
        const int r4 = t >> 6, c = t & 63;
        #pragma unroll
        for (int rr = 0; rr < 16; rr++) {
            int d = rr * 4 + r4;
            Ts[d][c] = W1[(size_t)(d0 + d) * Hc + h0 + c];
        }
        __syncthreads();
        #pragma unroll
        for (int rr = 0; rr < 16; rr++) {
            int hl = rr * 4 + r4;
            float v = Ts[c][hl];              // = W1[d0+c][h0+hl]
            unsigned short h16, l16;
            split_bf16(v, h16, l16);
            W1T_hi[(size_t)(h0 + hl) * Dc + d0 + c] = h16;
            W1T_lo[(size_t)(h0 + hl) * Dc + d0 + c] = l16;
        }
    } else {
        // ---- qb branch (verified in R7) ----
        const int bn = bid - 1032;
        qs[t] = q[bn * Qc + t];
        __syncthreads();

        const int h = t & 127, kq = t >> 7;   // kq = 0..1, 128 d each
        float acc = 0.f;
        const float* w = W1 + (size_t)(Dc + kq * 128) * Hc + h;
        #pragma unroll 8
        for (int d = 0; d < 128; ++d)
            acc += qs[kq * 128 + d] * w[(size_t)d * Hc];
        red[kq][h] = acc;
        __syncthreads();

        if (t < 128)
            qb[bn * Hc + t] = b1[t] + red[0][t] + red[1][t];
    }
}

// ---------------------------------------------------------------------------
// prep_M2: Mt[b][h][o] = sum_d W1[d][h]*obj[b][o][d] via MFMA on split bf16.
// ---------------------------------------------------------------------------
__global__ __launch_bounds__(256, 4) void prep_M2_kernel(
    const unsigned short* __restrict__ W1T_hi, const unsigned short* __restrict__ W1T_lo,
    const unsigned short* __restrict__ obj_hi, const unsigned short* __restrict__ obj_lo,
    unsigned short* __restrict__ Mt_hi, unsigned short* __restrict__ Mt_lo)
{
    const int t = threadIdx.x;
    const int wave = t >> 6, lane = t & 63;
    const int l15 = lane & 15, quad = lane >> 4;
    const int h0 = blockIdx.x * 64 + wave * 16;
    const int o0 = blockIdx.y * 32;
    const int b  = blockIdx.z;

    const size_t arow  = (size_t)(h0 + l15) * Dc;
    const size_t brow0 = ((size_t)b * Oc + o0 + l15) * Dc;
    const size_t brow1 = ((size_t)b * Oc + o0 + 16 + l15) * Dc;

    f32x4 acc0 = (f32x4)(0.f), acc1 = (f32x4)(0.f);
    #pragma unroll
    for (int ks = 0; ks < 8; ks++) {
        const int ko = ks * 32 + quad * 8;
        short8 Ah  = *(const short8*)(W1T_hi + arow + ko);
        short8 Al  = *(const short8*)(W1T_lo + arow + ko);
        short8 B0h = *(const short8*)(obj_hi + brow0 + ko);
        short8 B0l = *(const short8*)(obj_lo + brow0 + ko);
        short8 B1h = *(const short8*)(obj_hi + brow1 + ko);
        short8 B1l = *(const short8*)(obj_lo + brow1 + ko);
        acc0 = __builtin_amdgcn_mfma_f32_16x16x32_bf16(Al, B0l, acc0, 0, 0, 0);
        acc0 = __builtin_amdgcn_mfma_f32_16x16x32_bf16(Al, B0h, acc0, 0, 0, 0);
        acc0 = __builtin_amdgcn_mfma_f32_16x16x32_bf16(Ah, B0l, acc0, 0, 0, 0);
        acc0 = __builtin_amdgcn_mfma_f32_16x16x32_bf16(Ah, B0h, acc0, 0, 0, 0);
        acc1 = __builtin_amdgcn_mfma_f32_16x16x32_bf16(Al, B1l, acc1, 0, 0, 0);
        acc1 = __builtin_amdgcn_mfma_f32_16x16x32_bf16(Al, B1h, acc1, 0, 0, 0);
        acc1 = __builtin_amdgcn_mfma_f32_16x16x32_bf16(Ah, B1l, acc1, 0, 0, 0);
        acc1 = __builtin_amdgcn_mfma_f32_16x16x32_bf16(Ah, B1h, acc1, 0, 0, 0);
    }

    #pragma unroll
    for (int r = 0; r < 4; r++) {
        int hrow = h0 + quad * 4 + r;
        size_t base = ((size_t)b * Hc + hrow) * Oc + o0 + l15;
        unsigned short hh, ll;
        split_bf16(acc0[r], hh, ll);
        Mt_hi[base] = hh; Mt_lo[base] = ll;
        split_bf16(acc1[r], hh, ll);
        Mt_hi[base + 16] = hh; Mt_lo[base + 16] = ll;
    }
}

// ---------------------------------------------------------------------------
// main_half: grid (512) = 2 blocks per bn, 512 thr, 2 blocks/CU.
// R8: ping-pong A_s double-buffer -> 2 barriers/tile (was 3), and the
// 1-wave exp phase overlaps the 16-wave staging of the next tile.
// Phase-3 stays register-resident (sv). No fence/atomic finalize (R7 lesson:
// device-scope fences in every block serialize L2 -> 3x main regression).
// ---------------------------------------------------------------------------
__global__ __launch_bounds__(512, 4) void main_half_kernel(
    const float* __restrict__ att1, const int* __restrict__ tags,
    const unsigned short* __restrict__ Mt_hi, const unsigned short* __restrict__ Mt_lo,
    const float* __restrict__ qb, const float* __restrict__ W2,
    const float* __restrict__ b2, const void* __restrict__ tptr,
    float* __restrict__ out_part, float* __restrict__ z_part)
{
    __shared__ unsigned short A_s[2][64][136]; // ping-pong bf16 tiles, 34.8 KB
    __shared__ float part2[64][9];             // logit partials, +1 pad
    __shared__ float part3[16][132];           // end-of-kernel o-reduce, 8.4 KB
    __shared__ float e_s[64];
    __shared__ float qb_s[128], w2_s[128];

    const int t    = threadIdx.x;
    const int lane = t & 63;
    const int wave = t >> 6;          // 0..7
    const int l15  = lane & 15;
    const int quad = lane >> 4;
    const int blk  = blockIdx.x;      // 0..511
    const int bn   = blk >> 1;
    const int half = blk & 1;
    const int b    = bn >> 2;
    const int hw   = wave * 16;       // h-group base
    const int g3   = t >> 5;          // owned row group 0..15
    const int o4   = (t & 31) * 4;    // owned o base (4 consecutive o)

    const float* att_half = att1 + ((size_t)bn * Ac + half * 512) * Oc;

    // ---- prologue: tile-0 staging loads (HBM) ----
    f4 sv[4];
    #pragma unroll
    for (int s = 0; s < 4; s++) {
        int idx = t + 512 * s;
        sv[s] = *(const f4*)(att_half + (size_t)idx * 4);
    }

    // ---- B fragments (hi/lo), once per block ----
    const size_t brow = ((size_t)b * Hc + hw + l15) * Oc;
    short8 Bh[4], Bl[4];
    #pragma unroll
    for (int ks = 0; ks < 4; ks++) {
        const int ko = ks * 32 + quad * 8;
        Bh[ks] = *(const short8*)(Mt_hi + brow + ko);
        Bl[ks] = *(const short8*)(Mt_lo + brow + ko);
    }

    if (t < 128) { qb_s[t] = qb[bn * Hc + t]; w2_s[t] = W2[t]; }
    int tg_cur = (t < 64) ? tags[(size_t)bn * Ac + half * 512 + t] : 0;
    const float b2v  = b2[0];
    const float tval = decode_t(tptr);

    // ---- prologue: stage tile 0 into A_s[0] ----
    #pragma unroll
    for (int s = 0; s < 4; s++) {
        int idx = t + 512 * s;
        int r = idx >> 5, c4 = idx & 31;
        us4 h4;
        #pragma unroll
        for (int j = 0; j < 4; j++) h4[j] = bf16_rne(sv[s][j]);
        *(us4*)&A_s[0][r][c4 * 4] = h4;
    }
    __syncthreads();

    float z_reg = 0.f;
    f4 out4 = {0.f, 0.f, 0.f, 0.f};   // this thread's out[o4..o4+3] partial

    for (int tile = 0; tile < 8; ++tile) {
        const int buf = tile & 1;

        // ---- issue next-tile loads first (latency hides under MFMA) ----
        f4 nv[4];
        int tg_next = 0;
        if (tile < 7) {
            const float* np = att_half + (size_t)(tile + 1) * 64 * Oc;
            #pragma unroll
            for (int s = 0; s < 4; s++) {
                int idx = t + 512 * s;
                nv[s] = *(const f4*)(np + (size_t)idx * 4);
            }
            if (t < 64) tg_next = tags[(size_t)bn * Ac + half * 512 + (tile + 1) * 64 + t];
        }

        // ---- MFMA: A_rne * (Bhi + Blo) from A_s[buf] ----
        f32x4 acc[4];
        #pragma unroll
        for (int i = 0; i < 4; i++) acc[i] = (f32x4)(0.f);
        #pragma unroll
        for (int ks = 0; ks < 4; ks++) {
            const int ko = ks * 32 + quad * 8;
            #pragma unroll
            for (int i = 0; i < 4; i++) {
                short8 ah = *(const short8*)&A_s[buf][i * 16 + l15][ko];
                acc[i] = __builtin_amdgcn_mfma_f32_16x16x32_bf16(ah, Bh[ks], acc[i], 0, 0, 0);
                acc[i] = __builtin_amdgcn_mfma_f32_16x16x32_bf16(ah, Bl[ks], acc[i], 0, 0, 0);
            }
        }

        // ---- epilogue: +qb, relu, *W2; DPP row-reduce over the 16 h lanes ----
        // C/D layout: col(h) = l15, row(a) = i*16 + quad*4 + r
        {
            const float qbv = qb_s[hw + l15], w2v = w2_s[hw + l15];
            #pragma unroll
            for (int i = 0; i < 4; i++)
                #pragma unroll
                for (int r = 0; r < 4; r++) {
                    float v = acc[i][r] + qbv;
                    v = v > 0.f ? v : 0.f;
                    float s = row16_sum(v * w2v);   // VALU DPP, no LDS
                    if (l15 == 0)
                        part2[i * 16 + quad * 4 + r][wave] = s;
                }
        }
        __syncthreads();   // barrier1: part2 ready; A_s[buf] readers done

        // ---- exp (wave 0) OVERLAPPED with staging tile+1 into A_s[buf^1] ----
        if (t < 64) {
            float sum = b2v;
            #pragma unroll
            for (int x = 0; x < 8; x++) sum += part2[t][x];
            float logit = sum / tval;
            float e = (tg_cur > 0) ? __expf(logit) : 0.f;
            e_s[t] = e;
            z_reg += e;
        }
        if (tile < 7) {
            #pragma unroll
            for (int s = 0; s < 4; s++) {
                int idx = t + 512 * s;
                int r = idx >> 5, c4 = idx & 31;
                us4 h4;
                #pragma unroll
                for (int j = 0; j < 4; j++) h4[j] = bf16_rne(nv[s][j]);
                *(us4*)&A_s[buf ^ 1][r][c4 * 4] = h4;
            }
        }
        __syncthreads();   // barrier2: e_s ready; A_s[buf^1] staged

        // ---- phase 3: out4 += e[row]*sv — registers, zero tile LDS ----
        #pragma unroll
        for (int s = 0; s < 4; s++) {
            const float ev = e_s[g3 + 16 * s];
            out4[0] += ev * sv[s][0];
            out4[1] += ev * sv[s][1];
            out4[2] += ev * sv[s][2];
            out4[3] += ev * sv[s][3];
        }

        // ---- rotate prefetched tile in ----
        if (tile < 7) {
            #pragma unroll
            for (int s = 0; s < 4; s++) sv[s] = nv[s];
            tg_cur = tg_next;
        }
    }

    // ---- finalize: one part3 write + reduce, z reduce, store ----
    __syncthreads();
    *(f4*)&part3[g3][o4] = out4;
    __syncthreads();
    if (t < 128) {
        float s = 0.f;
        #pragma unroll
        for (int g = 0; g < 16; g++) s += part3[g][t];
        out_part[(size_t)blk * 128 + t] = s;
    }
    if (t < 64) {   // all z_reg live in wave 0
        float z = z_reg;
        #pragma unroll
        for (int off = 32; off > 0; off >>= 1) z += __shfl_down(z, off);
        if (t == 0) z_part[blk] = z;
    }
}

// ---------------------------------------------------------------------------
// finalize: out[bn,o] = (P0+P1)/(Z0+Z1)
// ---------------------------------------------------------------------------
__global__ __launch_bounds__(128) void finalize_kernel(
    const float* __restrict__ out_part, const float* __restrict__ z_part,
    float* __restrict__ out)
{
    const int bn = blockIdx.x;
    const int t  = threadIdx.x;
    const float Z = z_part[bn * 2] + z_part[bn * 2 + 1];
    const float v = out_part[(size_t)(bn * 2) * 128 + t]
                  + out_part[(size_t)(bn * 2 + 1) * 128 + t];
    out[(size_t)bn * 128 + t] = v / Z;
}

extern "C" void kernel_launch(void* const* d_in, const int* in_sizes, int n_in,
                              void* d_out, int out_size, void* d_ws, size_t ws_size,
                              hipStream_t stream)
{
    (void)in_sizes; (void)n_in; (void)out_size; (void)ws_size;

    const float* q    = (const float*)d_in[0];
    const float* att1 = (const float*)d_in[1];
    const float* obj  = (const float*)d_in[2];
    const int*   tags = (const int*)d_in[3];
    const float* W1   = (const float*)d_in[4];
    const float* b1   = (const float*)d_in[5];
    const float* W2   = (const float*)d_in[6];
    const float* b2   = (const float*)d_in[7];
    const void*  tptr = (const void*)d_in[8];
    float* out = (float*)d_out;

    char* wsb = (char*)d_ws;
    unsigned short* Mt_hi  = (unsigned short*)wsb;                           // 2 MB
    unsigned short* Mt_lo  = (unsigned short*)(wsb + (size_t) 2*1024*1024);  // 2 MB
    float* qbuf            = (float*)         (wsb + (size_t) 4*1024*1024);  // 128 KB
    float* out_part        = (float*)         (wsb + (size_t) 5*1024*1024);  // 256 KB
    float* z_part          = (float*)         (wsb + (size_t) 6*1024*1024);  // 2 KB
    unsigned short* W1T_hi = (unsigned short*)(wsb + (size_t) 7*1024*1024);  // 64 KB
    unsigned short* W1T_lo = (unsigned short*)(wsb + (size_t) 7*1024*1024 + 64*1024);
    unsigned short* obj_hi = (unsigned short*)(wsb + (size_t) 8*1024*1024);  // 4 MB
    unsigned short* obj_lo = (unsigned short*)(wsb + (size_t)12*1024*1024);  // 4 MB

    prep_combined_kernel<<<dim3(1032 + BN), 256, 0, stream>>>(
        obj, W1, q, b1, obj_hi, obj_lo, W1T_hi, W1T_lo, qbuf);
    prep_M2_kernel<<<dim3(2, 4, Bc), 256, 0, stream>>>(W1T_hi, W1T_lo, obj_hi, obj_lo,
                                                       Mt_hi, Mt_lo);
    main_half_kernel<<<dim3(2 * BN), 512, 0, stream>>>(att1, tags, Mt_hi, Mt_lo,
                                                       qbuf, W2, b2, tptr,
                                                       out_part, z_part);
    finalize_kernel<<<dim3(BN), 128, 0, stream>>>(out_part, z_part, out);
}

// Round 9
// 229.041 us; speedup vs baseline: 1.4660x; 1.0506x over previous
//
#include <hip/hip_runtime.h>
#include <math.h>

#define Bc 64
#define Nc 4
#define Ac 1024
#define Oc 128
#define Dc 256
#define Qc 256
#define Hc 128
#define BN (Bc*Nc)

using f4     = __attribute__((ext_vector_type(4))) float;
using f32x4  = __attribute__((ext_vector_type(4))) float;
using short8 = __attribute__((ext_vector_type(8))) short;
using us4    = __attribute__((ext_vector_type(4))) unsigned short;

__device__ inline float decode_t(const void* p) {
    int i = *(const int*)p;
    if (i >= 1 && i <= 1000000) return (float)i;
    return __int_as_float(i);
}

// round-to-nearest-even fp32 -> bf16
__device__ inline unsigned short bf16_rne(float x) {
    unsigned u = __builtin_bit_cast(unsigned, x);
    u += 0x7FFFu + ((u >> 16) & 1u);
    return (unsigned short)(u >> 16);
}

// split fp32 -> truncated bf16 hi + bf16(residual) lo.  x ~= hi + lo
__device__ inline void split_bf16(float x, unsigned short& hi, unsigned short& lo) {
    unsigned u = __builtin_bit_cast(unsigned, x);
    hi = (unsigned short)(u >> 16);
    float hif = __builtin_bit_cast(float, u & 0xFFFF0000u);
    float lof = x - hif;
    lo = (unsigned short)(__builtin_bit_cast(unsigned, lof) >> 16);
}

// VALU-only lane reduce within 16-lane rows via DPP row_ror (no LDS pipe).
template<int CTRL>
__device__ inline float dpp_ror_add(float x) {
    int yi = __builtin_amdgcn_update_dpp(0, __builtin_bit_cast(int, x),
                                         CTRL, 0xf, 0xf, true);
    return x + __builtin_bit_cast(float, yi);
}
__device__ inline float row16_sum(float v) {
    v = dpp_ror_add<0x128>(v);   // row_ror:8
    v = dpp_ror_add<0x124>(v);   // row_ror:4
    v = dpp_ror_add<0x122>(v);   // row_ror:2
    v = dpp_ror_add<0x121>(v);   // row_ror:1
    return v;
}

__device__ inline short8 pack_hi(const f4& a, const f4& b, short8& lo_out) {
    short8 hi;
    unsigned short h16, l16;
    #pragma unroll
    for (int j = 0; j < 4; j++) {
        split_bf16(a[j], h16, l16); hi[j] = (short)h16; lo_out[j] = (short)l16;
    }
    #pragma unroll
    for (int j = 0; j < 4; j++) {
        split_bf16(b[j], h16, l16); hi[4+j] = (short)h16; lo_out[4+j] = (short)l16;
    }
    return hi;
}

// ---------------------------------------------------------------------------
// prep_fused (verified in R7): ONE prep launch, no staging workspace.
//   blocks 0..511  : Mt[b][h][o] = sum_d W1[d][h]*obj[b][o][d] via MFMA;
//                    A (W1T) and B (obj) fragments from DIRECT fp32 loads
//                    + in-register hi/lo split.
//   blocks 512..767: qb[bn,h] = q[bn,:] @ W1q + b1[h].
// ---------------------------------------------------------------------------
__global__ __launch_bounds__(256, 2) void prep_fused_kernel(
    const float* __restrict__ obj, const float* __restrict__ W1,
    const float* __restrict__ q,   const float* __restrict__ b1,
    unsigned short* __restrict__ Mt_hi, unsigned short* __restrict__ Mt_lo,
    float* __restrict__ qb)
{
    __shared__ float qs[256];
    __shared__ float red[2][128];

    const int bid = blockIdx.x;
    const int t   = threadIdx.x;

    if (bid < 512) {
        // ---- M2 branch: 64h x 32o tile ----
        const int b    = bid >> 3;
        const int rr   = bid & 7;
        const int h0   = (rr & 1) * 64;
        const int o0   = (rr >> 1) * 32;
        const int wave = t >> 6, lane = t & 63;
        const int l15  = lane & 15, quad = lane >> 4;
        const int hh   = h0 + wave * 16 + l15;    // this lane's A row (h)

        short8 Ah[8], Al[8];
        #pragma unroll
        for (int ks = 0; ks < 8; ks++) {
            const int ko = ks * 32 + quad * 8;
            #pragma unroll
            for (int j = 0; j < 8; j++) {
                unsigned short h16, l16;
                split_bf16(W1[(size_t)(ko + j) * Hc + hh], h16, l16);
                Ah[ks][j] = (short)h16; Al[ks][j] = (short)l16;
            }
        }

        const float* ob0 = obj + ((size_t)b * Oc + o0 + l15) * Dc;
        const float* ob1 = obj + ((size_t)b * Oc + o0 + 16 + l15) * Dc;

        f32x4 acc0 = (f32x4)(0.f), acc1 = (f32x4)(0.f);
        #pragma unroll
        for (int ks = 0; ks < 8; ks++) {
            const int ko = ks * 32 + quad * 8;
            short8 B0l, B1l;
            short8 B0h = pack_hi(*(const f4*)(ob0 + ko), *(const f4*)(ob0 + ko + 4), B0l);
            short8 B1h = pack_hi(*(const f4*)(ob1 + ko), *(const f4*)(ob1 + ko + 4), B1l);
            acc0 = __builtin_amdgcn_mfma_f32_16x16x32_bf16(Al[ks], B0l, acc0, 0, 0, 0);
            acc0 = __builtin_amdgcn_mfma_f32_16x16x32_bf16(Al[ks], B0h, acc0, 0, 0, 0);
            acc0 = __builtin_amdgcn_mfma_f32_16x16x32_bf16(Ah[ks], B0l, acc0, 0, 0, 0);
            acc0 = __builtin_amdgcn_mfma_f32_16x16x32_bf16(Ah[ks], B0h, acc0, 0, 0, 0);
            acc1 = __builtin_amdgcn_mfma_f32_16x16x32_bf16(Al[ks], B1l, acc1, 0, 0, 0);
            acc1 = __builtin_amdgcn_mfma_f32_16x16x32_bf16(Al[ks], B1h, acc1, 0, 0, 0);
            acc1 = __builtin_amdgcn_mfma_f32_16x16x32_bf16(Ah[ks], B1l, acc1, 0, 0, 0);
            acc1 = __builtin_amdgcn_mfma_f32_16x16x32_bf16(Ah[ks], B1h, acc1, 0, 0, 0);
        }

        // C/D layout: col = l15 (o), row = quad*4 + r (h)
        #pragma unroll
        for (int r = 0; r < 4; r++) {
            int hrow = h0 + wave * 16 + quad * 4 + r;
            size_t base = ((size_t)b * Hc + hrow) * Oc + o0 + l15;
            unsigned short hh16, ll16;
            split_bf16(acc0[r], hh16, ll16);
            Mt_hi[base] = hh16; Mt_lo[base] = ll16;
            split_bf16(acc1[r], hh16, ll16);
            Mt_hi[base + 16] = hh16; Mt_lo[base + 16] = ll16;
        }
    } else {
        // ---- qb branch ----
        const int bn = bid - 512;
        qs[t] = q[bn * Qc + t];
        __syncthreads();

        const int h = t & 127, kq = t >> 7;   // kq = 0..1, 128 d each
        float acc = 0.f;
        const float* w = W1 + (size_t)(Dc + kq * 128) * Hc + h;
        #pragma unroll 8
        for (int d = 0; d < 128; ++d)
            acc += qs[kq * 128 + d] * w[(size_t)d * Hc];
        red[kq][h] = acc;
        __syncthreads();

        if (t < 128)
            qb[bn * Hc + t] = b1[t] + red[0][t] + red[1][t];
    }
}

// ---------------------------------------------------------------------------
// main_half (R8 structure, verified): grid (512) = 2 blocks per bn, 512 thr,
// 2 blocks/CU. Ping-pong A_s, 2 barriers/tile, exp overlapped with staging,
// register-resident phase-3. NO fence/atomic finalize (R7 lesson: device-
// scope fences in every block serialize L2 -> 3x main regression).
// ---------------------------------------------------------------------------
__global__ __launch_bounds__(512, 4) void main_half_kernel(
    const float* __restrict__ att1, const int* __restrict__ tags,
    const unsigned short* __restrict__ Mt_hi, const unsigned short* __restrict__ Mt_lo,
    const float* __restrict__ qb, const float* __restrict__ W2,
    const float* __restrict__ b2, const void* __restrict__ tptr,
    float* __restrict__ out_part, float* __restrict__ z_part)
{
    __shared__ unsigned short A_s[2][64][136]; // ping-pong bf16 tiles, 34.8 KB
    __shared__ float part2[64][9];             // logit partials, +1 pad
    __shared__ float part3[16][132];           // end-of-kernel o-reduce, 8.4 KB
    __shared__ float e_s[64];
    __shared__ float qb_s[128], w2_s[128];

    const int t    = threadIdx.x;
    const int lane = t & 63;
    const int wave = t >> 6;          // 0..7
    const int l15  = lane & 15;
    const int quad = lane >> 4;
    const int blk  = blockIdx.x;      // 0..511
    const int bn   = blk >> 1;
    const int half = blk & 1;
    const int b    = bn >> 2;
    const int hw   = wave * 16;       // h-group base
    const int g3   = t >> 5;          // owned row group 0..15
    const int o4   = (t & 31) * 4;    // owned o base (4 consecutive o)

    const float* att_half = att1 + ((size_t)bn * Ac + half * 512) * Oc;

    // ---- prologue: tile-0 staging loads (HBM) ----
    f4 sv[4];
    #pragma unroll
    for (int s = 0; s < 4; s++) {
        int idx = t + 512 * s;
        sv[s] = *(const f4*)(att_half + (size_t)idx * 4);
    }

    // ---- B fragments (hi/lo), once per block ----
    const size_t brow = ((size_t)b * Hc + hw + l15) * Oc;
    short8 Bh[4], Bl[4];
    #pragma unroll
    for (int ks = 0; ks < 4; ks++) {
        const int ko = ks * 32 + quad * 8;
        Bh[ks] = *(const short8*)(Mt_hi + brow + ko);
        Bl[ks] = *(const short8*)(Mt_lo + brow + ko);
    }

    if (t < 128) { qb_s[t] = qb[bn * Hc + t]; w2_s[t] = W2[t]; }
    int tg_cur = (t < 64) ? tags[(size_t)bn * Ac + half * 512 + t] : 0;
    const float b2v  = b2[0];
    const float tval = decode_t(tptr);

    // ---- prologue: stage tile 0 into A_s[0] ----
    #pragma unroll
    for (int s = 0; s < 4; s++) {
        int idx = t + 512 * s;
        int r = idx >> 5, c4 = idx & 31;
        us4 h4;
        #pragma unroll
        for (int j = 0; j < 4; j++) h4[j] = bf16_rne(sv[s][j]);
        *(us4*)&A_s[0][r][c4 * 4] = h4;
    }
    __syncthreads();

    float z_reg = 0.f;
    f4 out4 = {0.f, 0.f, 0.f, 0.f};   // this thread's out[o4..o4+3] partial

    for (int tile = 0; tile < 8; ++tile) {
        const int buf = tile & 1;

        // ---- issue next-tile loads first (latency hides under MFMA) ----
        f4 nv[4];
        int tg_next = 0;
        if (tile < 7) {
            const float* np = att_half + (size_t)(tile + 1) * 64 * Oc;
            #pragma unroll
            for (int s = 0; s < 4; s++) {
                int idx = t + 512 * s;
                nv[s] = *(const f4*)(np + (size_t)idx * 4);
            }
            if (t < 64) tg_next = tags[(size_t)bn * Ac + half * 512 + (tile + 1) * 64 + t];
        }

        // ---- MFMA: A_rne * (Bhi + Blo) from A_s[buf] ----
        f32x4 acc[4];
        #pragma unroll
        for (int i = 0; i < 4; i++) acc[i] = (f32x4)(0.f);
        #pragma unroll
        for (int ks = 0; ks < 4; ks++) {
            const int ko = ks * 32 + quad * 8;
            #pragma unroll
            for (int i = 0; i < 4; i++) {
                short8 ah = *(const short8*)&A_s[buf][i * 16 + l15][ko];
                acc[i] = __builtin_amdgcn_mfma_f32_16x16x32_bf16(ah, Bh[ks], acc[i], 0, 0, 0);
                acc[i] = __builtin_amdgcn_mfma_f32_16x16x32_bf16(ah, Bl[ks], acc[i], 0, 0, 0);
            }
        }

        // ---- epilogue: +qb, relu, *W2; DPP row-reduce over the 16 h lanes ----
        // C/D layout: col(h) = l15, row(a) = i*16 + quad*4 + r
        {
            const float qbv = qb_s[hw + l15], w2v = w2_s[hw + l15];
            #pragma unroll
            for (int i = 0; i < 4; i++)
                #pragma unroll
                for (int r = 0; r < 4; r++) {
                    float v = acc[i][r] + qbv;
                    v = v > 0.f ? v : 0.f;
                    float s = row16_sum(v * w2v);   // VALU DPP, no LDS
                    if (l15 == 0)
                        part2[i * 16 + quad * 4 + r][wave] = s;
                }
        }
        __syncthreads();   // barrier1: part2 ready; A_s[buf] readers done

        // ---- exp (wave 0) OVERLAPPED with staging tile+1 into A_s[buf^1] ----
        if (t < 64) {
            float sum = b2v;
            #pragma unroll
            for (int x = 0; x < 8; x++) sum += part2[t][x];
            float logit = sum / tval;
            float e = (tg_cur > 0) ? __expf(logit) : 0.f;
            e_s[t] = e;
            z_reg += e;
        }
        if (tile < 7) {
            #pragma unroll
            for (int s = 0; s < 4; s++) {
                int idx = t + 512 * s;
                int r = idx >> 5, c4 = idx & 31;
                us4 h4;
                #pragma unroll
                for (int j = 0; j < 4; j++) h4[j] = bf16_rne(nv[s][j]);
                *(us4*)&A_s[buf ^ 1][r][c4 * 4] = h4;
            }
        }
        __syncthreads();   // barrier2: e_s ready; A_s[buf^1] staged

        // ---- phase 3: out4 += e[row]*sv — registers, zero tile LDS ----
        #pragma unroll
        for (int s = 0; s < 4; s++) {
            const float ev = e_s[g3 + 16 * s];
            out4[0] += ev * sv[s][0];
            out4[1] += ev * sv[s][1];
            out4[2] += ev * sv[s][2];
            out4[3] += ev * sv[s][3];
        }

        // ---- rotate prefetched tile in ----
        if (tile < 7) {
            #pragma unroll
            for (int s = 0; s < 4; s++) sv[s] = nv[s];
            tg_cur = tg_next;
        }
    }

    // ---- finalize: one part3 write + reduce, z reduce, store ----
    __syncthreads();
    *(f4*)&part3[g3][o4] = out4;
    __syncthreads();
    if (t < 128) {
        float s = 0.f;
        #pragma unroll
        for (int g = 0; g < 16; g++) s += part3[g][t];
        out_part[(size_t)blk * 128 + t] = s;
    }
    if (t < 64) {   // all z_reg live in wave 0
        float z = z_reg;
        #pragma unroll
        for (int off = 32; off > 0; off >>= 1) z += __shfl_down(z, off);
        if (t == 0) z_part[blk] = z;
    }
}

// ---------------------------------------------------------------------------
// finalize: out[bn,o] = (P0+P1)/(Z0+Z1)
// ---------------------------------------------------------------------------
__global__ __launch_bounds__(128) void finalize_kernel(
    const float* __restrict__ out_part, const float* __restrict__ z_part,
    float* __restrict__ out)
{
    const int bn = blockIdx.x;
    const int t  = threadIdx.x;
    const float Z = z_part[bn * 2] + z_part[bn * 2 + 1];
    const float v = out_part[(size_t)(bn * 2) * 128 + t]
                  + out_part[(size_t)(bn * 2 + 1) * 128 + t];
    out[(size_t)bn * 128 + t] = v / Z;
}

extern "C" void kernel_launch(void* const* d_in, const int* in_sizes, int n_in,
                              void* d_out, int out_size, void* d_ws, size_t ws_size,
                              hipStream_t stream)
{
    (void)in_sizes; (void)n_in; (void)out_size; (void)ws_size;

    const float* q    = (const float*)d_in[0];
    const float* att1 = (const float*)d_in[1];
    const float* obj  = (const float*)d_in[2];
    const int*   tags = (const int*)d_in[3];
    const float* W1   = (const float*)d_in[4];
    const float* b1   = (const float*)d_in[5];
    const float* W2   = (const float*)d_in[6];
    const float* b2   = (const float*)d_in[7];
    const void*  tptr = (const void*)d_in[8];
    float* out = (float*)d_out;

    char* wsb = (char*)d_ws;
    unsigned short* Mt_hi = (unsigned short*)wsb;                          // 2 MB
    unsigned short* Mt_lo = (unsigned short*)(wsb + (size_t)2*1024*1024);  // 2 MB
    float* qbuf     = (float*)(wsb + (size_t)4*1024*1024);  // 128 KB
    float* out_part = (float*)(wsb + (size_t)5*1024*1024);  // 256 KB
    float* z_part   = (float*)(wsb + (size_t)6*1024*1024);  // 2 KB

    prep_fused_kernel<<<dim3(512 + BN), 256, 0, stream>>>(obj, W1, q, b1,
                                                          Mt_hi, Mt_lo, qbuf);
    main_half_kernel<<<dim3(2 * BN), 512, 0, stream>>>(att1, tags, Mt_hi, Mt_lo,
                                                       qbuf, W2, b2, tptr,
                                                       out_part, z_part);
    finalize_kernel<<<dim3(BN), 128, 0, stream>>>(out_part, z_part, out);
}